// Round 4
// baseline (93.758 us; speedup 1.0000x reference)
//
#include <hip/hip_runtime.h>
#include <hip/hip_bf16.h>

#define DIM 1024
#define SEQ 4096
#define NB 4
#define MROWS (NB * SEQ)   // 16384
#define NC 64              // chunks per sequence
#define CL (SEQ / NC)      // 64 L-positions per chunk

// GEMM tiling
#define BM 256
#define BN 256
#define BK 32
#define NT (DIM / BK)      // 32 K-tiles
#define TILE_LDS 32768     // A half (16KB) + B half (16KB) per K-tile
#define GEMM_LDS (4 * TILE_LDS)   // 128 KiB, 4-buffer rotation

typedef __attribute__((ext_vector_type(8))) short bf16x8;
typedef __attribute__((ext_vector_type(4))) float f32x4;

static __device__ __forceinline__ unsigned short f2bf(float f) {
    union { float f; unsigned u; } v; v.f = f;
    unsigned r = v.u + 0x7FFF + ((v.u >> 16) & 1);
    return (unsigned short)(r >> 16);
}

static __device__ __forceinline__ float bf2f(unsigned short h) {
    union { unsigned u; float f; } v; v.u = ((unsigned)h) << 16;
    return v.f;
}

static __device__ __forceinline__ void gload_lds16(const void* g, void* l) {
    __builtin_amdgcn_global_load_lds((const __attribute__((address_space(1))) void*)g,
                                     (__attribute__((address_space(3))) void*)l, 16, 0, 0);
}

// ---- convert x and W fp32 -> bf16 ----
__global__ void convert_kernel(const float* __restrict__ x, const float* __restrict__ W,
                               unsigned short* __restrict__ xb, unsigned short* __restrict__ wb) {
    const long long NX4 = (long long)MROWS * DIM / 4;
    const long long NW4 = (long long)DIM * DIM / 4;
    long long t = (long long)blockIdx.x * blockDim.x + threadIdx.x;
    if (t < NX4) {
        float4 v = ((const float4*)x)[t];
        ushort4 o;
        o.x = f2bf(v.x); o.y = f2bf(v.y); o.z = f2bf(v.z); o.w = f2bf(v.w);
        ((ushort4*)xb)[t] = o;
    } else if (t < NX4 + NW4) {
        long long u = t - NX4;
        float4 v = ((const float4*)W)[u];
        ushort4 o;
        o.x = f2bf(v.x); o.y = f2bf(v.y); o.z = f2bf(v.z); o.w = f2bf(v.w);
        ((ushort4*)wb)[u] = o;
    }
}

// Stage one K-tile half (A or B) of tile into buffer q.
// LDS linear [256 rows][64 B]; the 4 16B-slots of each row are stored XOR-permuted:
// LDS slot s holds global chunk s ^ ((row>>1)&3). For the staging thread the
// XOR term ((row>>1)&3) == ((lane>>3)&3), so the source chunk is lane-only.
static __device__ __forceinline__ void stage_A(const unsigned short* __restrict__ A, char* smem,
                                               int q, int m0, int ks, int w, int lane) {
    const int c16 = (lane & 3) ^ ((lane >> 3) & 3);
#pragma unroll
    for (int r = 0; r < 2; ++r) {
        int row = r * 128 + w * 16 + (lane >> 2);
        const unsigned short* g = A + (size_t)(m0 + row) * DIM + ks + c16 * 8;
        char* l = smem + q * TILE_LDS + (r * 128 + w * 16) * 64 + lane * 16;
        gload_lds16(g, l);
    }
}

static __device__ __forceinline__ void stage_B(const unsigned short* __restrict__ Bm, char* smem,
                                               int q, int n0, int ks, int w, int lane) {
    const int c16 = (lane & 3) ^ ((lane >> 3) & 3);
#pragma unroll
    for (int r = 0; r < 2; ++r) {
        int row = r * 128 + w * 16 + (lane >> 2);
        const unsigned short* g = Bm + (size_t)(n0 + row) * DIM + ks + c16 * 8;
        char* l = smem + q * TILE_LDS + 16384 + (r * 128 + w * 16) * 64 + lane * 16;
        gload_lds16(g, l);
    }
}

// ---- GEMM: V[m][n] = bf16( sum_k A[m][k]*B[n][k] + bias[n] ) ----
// 256x256 tile, BK=32, 4-deep LDS rotation, counted vmcnt(8), 8 waves (2Mx4N),
// m201-style per-phase double-barrier lockstep + setprio.
__global__ __launch_bounds__(512, 2) void gemm_kernel(const unsigned short* __restrict__ A,
                                                      const unsigned short* __restrict__ Bm,
                                                      const float* __restrict__ bias,
                                                      unsigned short* __restrict__ V) {
    extern __shared__ char smem[];
    const int tid  = threadIdx.x;
    const int lane = tid & 63;
    const int w    = tid >> 6;           // wave 0..7
    const int wm   = w >> 2;             // 0..1
    const int wn   = w & 3;              // 0..3
    const int wr   = wm * 128;           // wave row offset (M)
    const int wc   = wn * 64;            // wave col offset (N)
    const int rl   = lane & 15;
    const int rh   = lane >> 4;
    const int swz  = (rh ^ ((rl >> 1) & 3)) * 16;  // undo the stored XOR permutation
    const int m0   = blockIdx.x * BM;
    const int n0   = blockIdx.y * BN;

    f32x4 acc[8][4];
#pragma unroll
    for (int m = 0; m < 8; ++m)
#pragma unroll
        for (int n = 0; n < 4; ++n)
            acc[m][n] = (f32x4){0.f, 0.f, 0.f, 0.f};

    // preload bias for this thread's 4 output columns
    float bv[4];
#pragma unroll
    for (int nf = 0; nf < 4; ++nf)
        bv[nf] = bias[n0 + wc + nf * 16 + rl];

    // prologue: stage tiles 0,1,2 (12 loads/thread in flight)
#pragma unroll
    for (int s = 0; s < 3; ++s) {
        stage_A(A, smem, s, m0, s * BK, w, lane);
        stage_B(Bm, smem, s, n0, s * BK, w, lane);
    }
    // tile 0 resident after: own oldest 4 landed + all waves at barrier
    asm volatile("s_waitcnt vmcnt(8)" ::: "memory");
    __builtin_amdgcn_s_barrier();

#pragma unroll 4
    for (int t = 0; t < NT; ++t) {
        const int q  = t & 3;
        const int qn = (t + 3) & 3;
        const int ksn = ((t + 3) & (NT - 1)) * BK;   // tail wraps into dead buffers
        char* base = smem + q * TILE_LDS;

        // ===== phase A: mf 0..3 x nf 0..3 =====
        bf16x8 bfr[4];
#pragma unroll
        for (int nf = 0; nf < 4; ++nf)
            bfr[nf] = *(const bf16x8*)(base + 16384 + (wc + nf * 16 + rl) * 64 + swz);
        bf16x8 af[4];
#pragma unroll
        for (int mf = 0; mf < 4; ++mf)
            af[mf] = *(const bf16x8*)(base + (wr + mf * 16 + rl) * 64 + swz);
        stage_A(A, smem, qn, m0, ksn, w, lane);
        __builtin_amdgcn_sched_barrier(0);
        __builtin_amdgcn_s_barrier();
        asm volatile("s_waitcnt lgkmcnt(0)" ::: "memory");
        __builtin_amdgcn_sched_barrier(0);
        __builtin_amdgcn_s_setprio(1);
#pragma unroll
        for (int mf = 0; mf < 4; ++mf)
#pragma unroll
            for (int nf = 0; nf < 4; ++nf)
                acc[mf][nf] = __builtin_amdgcn_mfma_f32_16x16x32_bf16(af[mf], bfr[nf], acc[mf][nf], 0, 0, 0);
        __builtin_amdgcn_s_setprio(0);
        __builtin_amdgcn_sched_barrier(0);
        __builtin_amdgcn_s_barrier();

        // ===== phase B: mf 4..7 x nf 0..3 (bfr reused in registers) =====
#pragma unroll
        for (int mf = 0; mf < 4; ++mf)
            af[mf] = *(const bf16x8*)(base + (wr + (mf + 4) * 16 + rl) * 64 + swz);
        stage_B(Bm, smem, qn, n0, ksn, w, lane);
        // counted wait: keep 2 tiles (8 loads) in flight; tile t+1 resident after barrier
        asm volatile("s_waitcnt vmcnt(8)" ::: "memory");
        __builtin_amdgcn_sched_barrier(0);
        __builtin_amdgcn_s_barrier();
        asm volatile("s_waitcnt lgkmcnt(0)" ::: "memory");
        __builtin_amdgcn_sched_barrier(0);
        __builtin_amdgcn_s_setprio(1);
#pragma unroll
        for (int mf = 0; mf < 4; ++mf)
#pragma unroll
            for (int nf = 0; nf < 4; ++nf)
                acc[mf + 4][nf] = __builtin_amdgcn_mfma_f32_16x16x32_bf16(af[mf], bfr[nf], acc[mf + 4][nf], 0, 0, 0);
        __builtin_amdgcn_s_setprio(0);
        __builtin_amdgcn_sched_barrier(0);
        __builtin_amdgcn_s_barrier();
    }

    // epilogue: C/D layout col = lane&15, row = (lane>>4)*4 + reg; store bf16
#pragma unroll
    for (int mf = 0; mf < 8; ++mf) {
#pragma unroll
        for (int nf = 0; nf < 4; ++nf) {
            int gcol = n0 + wc + nf * 16 + rl;
#pragma unroll
            for (int j = 0; j < 4; ++j) {
                int grow = m0 + wr + mf * 16 + rh * 4 + j;
                V[(size_t)grow * DIM + gcol] = f2bf(acc[mf][nf][j] + bv[nf]);
            }
        }
    }
}

// ---- pass A: per-chunk sums of v*cos, v*sin. 2 e-columns/thread ----
__global__ void passA_kernel(const unsigned short* __restrict__ val, const float* __restrict__ ph,
                             float* __restrict__ pr, float* __restrict__ pi) {
    int t  = blockIdx.x * 256 + threadIdx.x;
    int c  = blockIdx.y;
    int bb = blockIdx.z;
    const ushort2* v = (const ushort2*)val + ((size_t)bb * SEQ + (size_t)c * CL) * (DIM / 2) + t;
    const float2*  p = (const float2*)ph + (size_t)c * CL * (DIM / 2) + t;
    float sr0 = 0.f, si0 = 0.f, sr1 = 0.f, si1 = 0.f;
    for (int l = 0; l < CL; ++l) {
        ushort2 vv = v[(size_t)l * (DIM / 2)];
        float2  pp = p[(size_t)l * (DIM / 2)];
        float v0 = bf2f(vv.x), v1 = bf2f(vv.y);
        float s0, c0, s1, c1;
        __sincosf(pp.x, &s0, &c0);
        __sincosf(pp.y, &s1, &c1);
        sr0 += v0 * c0; si0 += v0 * s0;
        sr1 += v1 * c1; si1 += v1 * s1;
    }
    size_t idx = ((size_t)bb * NC + c) * DIM + 2 * t;
    pr[idx] = sr0; pr[idx + 1] = sr1;
    pi[idx] = si0; pi[idx + 1] = si1;
}

// ---- pass B: exclusive scan of chunk partials over c ----
__global__ void passB_kernel(float* __restrict__ pr, float* __restrict__ pi) {
    int t = blockIdx.x * 256 + threadIdx.x;
    int bb = t >> 10;
    int e  = t & 1023;
    float r = 0.f, im = 0.f;
    for (int c = 0; c < NC; ++c) {
        size_t idx = ((size_t)bb * NC + c) * DIM + e;
        float tr = pr[idx], ti = pi[idx];
        pr[idx] = r; pi[idx] = im;
        r += tr; im += ti;
    }
}

// ---- pass C: running cumsum + retrieval + norm -> fp32 out ----
__global__ void passC_kernel(const unsigned short* __restrict__ val, const float* __restrict__ ph,
                             const float* __restrict__ pr, const float* __restrict__ pi,
                             float* __restrict__ out) {
    int t  = blockIdx.x * 256 + threadIdx.x;
    int c  = blockIdx.y;
    int bb = blockIdx.z;
    size_t base = ((size_t)bb * SEQ + (size_t)c * CL) * (DIM / 2) + t;
    const ushort2* v = (const ushort2*)val + base;
    const float2*  p = (const float2*)ph + (size_t)c * CL * (DIM / 2) + t;
    float2* o = (float2*)out + base;
    size_t pidx = ((size_t)bb * NC + c) * DIM + 2 * t;
    float ar0 = pr[pidx], ar1 = pr[pidx + 1];
    float ai0 = pi[pidx], ai1 = pi[pidx + 1];
    const int l0 = c * CL;
    for (int l = 0; l < CL; ++l) {
        ushort2 vv = v[(size_t)l * (DIM / 2)];
        float2  pp = p[(size_t)l * (DIM / 2)];
        float v0 = bf2f(vv.x), v1 = bf2f(vv.y);
        float s0, c0, s1, c1;
        __sincosf(pp.x, &s0, &c0);
        __sincosf(pp.y, &s1, &c1);
        ar0 += v0 * c0; ai0 += v0 * s0;
        ar1 += v1 * c1; ai1 += v1 * s1;
        float rn = rsqrtf((float)(l0 + l + 1));
        float2 ov;
        ov.x = (ar0 * c0 + ai0 * s0) * rn;
        ov.y = (ar1 * c1 + ai1 * s1) * rn;
        o[(size_t)l * (DIM / 2)] = ov;
    }
}

extern "C" void kernel_launch(void* const* d_in, const int* in_sizes, int n_in,
                              void* d_out, int out_size, void* d_ws, size_t ws_size,
                              hipStream_t stream) {
    const float* x  = (const float*)d_in[0];
    const float* ph = (const float*)d_in[1];
    const float* W  = (const float*)d_in[2];
    const float* b  = (const float*)d_in[3];
    float* out = (float*)d_out;

    // d_out doubles as scratch for bf16 inputs until passC overwrites it
    unsigned short* xb = (unsigned short*)d_out;
    unsigned short* wb = xb + (size_t)MROWS * DIM;

    // ws: value bf16 [0,32MiB), pr, pi
    unsigned short* vb = (unsigned short*)d_ws;
    float* pr = (float*)(vb + (size_t)MROWS * DIM);
    float* pi = pr + (size_t)NB * NC * DIM;

    (void)hipFuncSetAttribute((const void*)gemm_kernel,
                              hipFuncAttributeMaxDynamicSharedMemorySize, GEMM_LDS);

    // 1) convert
    {
        long long total4 = (long long)MROWS * DIM / 4 + (long long)DIM * DIM / 4;
        int blocks = (int)((total4 + 255) / 256);
        convert_kernel<<<blocks, 256, 0, stream>>>(x, W, xb, wb);
    }
    // 2) GEMM -> bf16 value into ws
    {
        dim3 grid(MROWS / BM, DIM / BN);
        gemm_kernel<<<grid, 512, GEMM_LDS, stream>>>(xb, wb, b, vb);
    }
    // 3) chunk partial sums
    {
        dim3 grid(DIM / 512, NC, NB);
        passA_kernel<<<grid, 256, 0, stream>>>(vb, ph, pr, pi);
    }
    // 4) scan partials
    passB_kernel<<<16, 256, 0, stream>>>(pr, pi);
    // 5) final cumsum + retrieve + norm -> fp32 d_out
    {
        dim3 grid(DIM / 512, NC, NB);
        passC_kernel<<<grid, 256, 0, stream>>>(vb, ph, pr, pi, out);
    }
}